// Round 2
// baseline (77.146 us; speedup 1.0000x reference)
//
#include <hip/hip_runtime.h>

#define EPS_F 1e-6f
#define LOG2E 1.4426950408889634f

typedef float f4a __attribute__((ext_vector_type(4), aligned(16)));

// Force a (known-uniform) float into an SGPR.
__device__ __forceinline__ float rfl(float x) {
    return __builtin_bit_cast(float, __builtin_amdgcn_readfirstlane(__builtin_bit_cast(int, x)));
}

// Kernel 1: partial sums over 64-wide n-chunks.
// grid = 2048 blocks = B(8) x n-chunks(16) x m-tiles(16); block = 256 thr = 4 waves.
// lane <-> m (64 m's per block, same set for all 4 waves); wave w sums n in
// [chunk*64 + w*16, +16). 2048 blocks = 2 rounds/CU so round-2 staging pipelines
// behind round-1 compute (the old 1024-block grid was exactly one round: every
// wave paid cold staging latency with nothing to overlap it).
// feat/xa rows staged in LDS (rows padded to 16/4 floats -> 16B-aligned b128
// reads); inner-loop ds_reads are all-lanes-same-address -> HW broadcast.
// unroll 4 (not 8): ~105 live VGPRs < 128 cap of __launch_bounds__(256,4).
__global__ __launch_bounds__(256, 4) void icgp_partial_kernel(
    const float* __restrict__ xa,       // (B, 1024, 1, 3)
    const float* __restrict__ feat,     // (B, 1024, 5, 3)
    const float* __restrict__ xt,       // (B, 1024, 1, 3)
    const float* __restrict__ log_std,  // (1, 5, 3)
    float* __restrict__ pws)            // (16, B*1024*15) partials
{
    // staging: sfeat = lds[0..1023] (64 rows x 16), sxa = lds[1024..1279]
    // (64 rows x 4); epilogue reuses lds[0..3839] (256 x 15).
    __shared__ float lds[3840];         // 15360 B

    const int bid  = blockIdx.x;
    const int mt   = bid & 15;          // m-tile (64 m's)
    const int nc   = (bid >> 4) & 15;   // n-chunk (64 n's)
    const int b    = bid >> 8;
    const int tid  = threadIdx.x;
    const int wv   = __builtin_amdgcn_readfirstlane(tid >> 6); // 0..3, uniform
    const int lane = tid & 63;
    const int m    = mt * 64 + lane;
    const int n0   = nc * 64;

    // ---- stage feat (960 floats) and xa (192 floats) into padded LDS ----
    const float* __restrict__ fg = feat + ((size_t)b * 1024 + n0) * 15; // 16B-aligned
    if (tid < 240) {
        const f4a v = *(const f4a*)(fg + tid * 4);
        #pragma unroll
        for (int e = 0; e < 4; ++e) {
            const int g = tid * 4 + e;
            const int r = g / 15, c = g - r * 15;
            lds[r * 16 + c] = v[e];
        }
    }
    const float* __restrict__ ag = xa + ((size_t)b * 1024 + n0) * 3;    // 16B-aligned
    if (tid < 48) {
        const f4a v = *(const f4a*)(ag + tid * 4);
        #pragma unroll
        for (int e = 0; e < 4; ++e) {
            const int g = tid * 4 + e;
            const int r = g / 3, c = g - r * 3;
            lds[1024 + r * 4 + c] = v[e];
        }
    }

    // ---- coefficients: wt = exp2(coef*(xa-xt)^2), coef = -0.5*log2e/std^2 ----
    float coef[15];
    #pragma unroll
    for (int kc = 0; kc < 15; ++kc) {
        const float s = __expf(log_std[kc]) + EPS_F;
        coef[kc] = rfl(-0.5f * LOG2E / (s * s));
    }
    bool uni = true;
    #pragma unroll
    for (int k = 1; k < 5; ++k)
        #pragma unroll
        for (int c = 0; c < 3; ++c)
            uni = uni && (coef[k * 3 + c] == coef[c]);

    const float t0 = xt[(b * 1024 + m) * 3 + 0];
    const float t1 = xt[(b * 1024 + m) * 3 + 1];
    const float t2 = xt[(b * 1024 + m) * 3 + 2];

    __syncthreads();

    float acc[15];
    #pragma unroll
    for (int kc = 0; kc < 15; ++kc) acc[kc] = 0.0f;

    const int rb = wv * 16;             // this wave's first LDS row

    if (uni) {
        const float c0 = coef[0], c1 = coef[1], c2 = coef[2];
        #pragma unroll 4
        for (int i = 0; i < 16; ++i) {
            const float* __restrict__ row = &lds[(rb + i) * 16];
            const f4a fA = *(const f4a*)(row);        // kc 0..3
            const f4a fB = *(const f4a*)(row + 4);    // kc 4..7
            const f4a fC = *(const f4a*)(row + 8);    // kc 8..11
            const f4a fD = *(const f4a*)(row + 12);   // kc 12..14 (+pad)
            const f4a av = *(const f4a*)(&lds[1024 + (rb + i) * 4]); // xa (+pad)
            float d0 = av.x - t0; d0 *= d0;
            float d1 = av.y - t1; d1 *= d1;
            float d2 = av.z - t2; d2 *= d2;
            const float w0 = __builtin_amdgcn_exp2f(d0 * c0);
            const float w1 = __builtin_amdgcn_exp2f(d1 * c1);
            const float w2 = __builtin_amdgcn_exp2f(d2 * c2);
            acc[0]  += w0 * fA.x;  acc[1]  += w1 * fA.y;  acc[2]  += w2 * fA.z;
            acc[3]  += w0 * fA.w;  acc[4]  += w1 * fB.x;  acc[5]  += w2 * fB.y;
            acc[6]  += w0 * fB.z;  acc[7]  += w1 * fB.w;  acc[8]  += w2 * fC.x;
            acc[9]  += w0 * fC.y;  acc[10] += w1 * fC.z;  acc[11] += w2 * fC.w;
            acc[12] += w0 * fD.x;  acc[13] += w1 * fD.y;  acc[14] += w2 * fD.z;
        }
    } else {
        // General path: 15 exps per n (correct for arbitrary log_std).
        for (int i = 0; i < 16; ++i) {
            const float* __restrict__ row = &lds[(rb + i) * 16];
            float fv[16];
            *(f4a*)(fv)      = *(const f4a*)(row);
            *(f4a*)(fv + 4)  = *(const f4a*)(row + 4);
            *(f4a*)(fv + 8)  = *(const f4a*)(row + 8);
            *(f4a*)(fv + 12) = *(const f4a*)(row + 12);
            const f4a av = *(const f4a*)(&lds[1024 + (rb + i) * 4]);
            float dd[3];
            dd[0] = av.x - t0; dd[0] *= dd[0];
            dd[1] = av.y - t1; dd[1] *= dd[1];
            dd[2] = av.z - t2; dd[2] *= dd[2];
            #pragma unroll
            for (int k = 0; k < 5; ++k)
                #pragma unroll
                for (int c = 0; c < 3; ++c)
                    acc[k * 3 + c] +=
                        __builtin_amdgcn_exp2f(dd[c] * coef[k * 3 + c]) * fv[k * 3 + c];
        }
    }

    // ---- in-block combine of the 4 wave-partials, plain store to pws ----
    __syncthreads();                    // all waves done reading staging
    #pragma unroll
    for (int kc = 0; kc < 15; ++kc) lds[tid * 15 + kc] = acc[kc];
    __syncthreads();

    float* __restrict__ pb = pws + (size_t)nc * 122880
                                 + ((size_t)b * 1024 + mt * 64) * 15;
    #pragma unroll
    for (int j = 0; j < 4; ++j) {
        const int oidx = j * 256 + tid;         // 0..959
        if (oidx < 960) {
            const int mm = oidx / 15, kc = oidx - mm * 15;
            float s = 0.0f;
            #pragma unroll
            for (int w = 0; w < 4; ++w)
                s += lds[(w * 64 + mm) * 15 + kc];
            pb[oidx] = s;                        // coalesced
        }
    }
}

// Kernel 2: sum the 16 n-chunk slices, float4-vectorized, fully coalesced.
// 30720 float4 outputs = 120 blocks x 256 threads.
__global__ __launch_bounds__(256) void icgp_reduce_kernel(
    const float* __restrict__ pws, float* __restrict__ out)
{
    const int idx4 = blockIdx.x * 256 + threadIdx.x;   // < 30720
    const f4a* __restrict__ p4 = (const f4a*)pws;
    f4a s = {0.0f, 0.0f, 0.0f, 0.0f};
    #pragma unroll
    for (int ns = 0; ns < 16; ++ns) {
        const f4a v = p4[(size_t)ns * 30720 + idx4];
        s.x += v.x; s.y += v.y; s.z += v.z; s.w += v.w;
    }
    ((f4a*)out)[idx4] = s;
}

extern "C" void kernel_launch(void* const* d_in, const int* in_sizes, int n_in,
                              void* d_out, int out_size, void* d_ws, size_t ws_size,
                              hipStream_t stream) {
    const float* xa      = (const float*)d_in[0];  // (8,1024,1,3)
    const float* feat    = (const float*)d_in[1];  // (8,1024,5,3)
    const float* xt      = (const float*)d_in[2];  // (8,1024,1,3)
    const float* log_std = (const float*)d_in[3];  // (1,5,3)
    float* out = (float*)d_out;                    // (8,1024,5,3)
    float* pws = (float*)d_ws;                     // 16 x 122880 floats = 7.86 MB

    icgp_partial_kernel<<<dim3(2048), dim3(256), 0, stream>>>(xa, feat, xt, log_std, pws);
    icgp_reduce_kernel<<<dim3(120), dim3(256), 0, stream>>>(pws, out);
}

// Round 3
// 76.505 us; speedup vs baseline: 1.0084x; 1.0084x over previous
//
#include <hip/hip_runtime.h>

#define EPS_F 1e-6f
#define LOG2E 1.4426950408889634f

typedef float f4a __attribute__((ext_vector_type(4), aligned(16)));

// Force a (known-uniform) float into an SGPR.
__device__ __forceinline__ float rfl(float x) {
    return __builtin_bit_cast(float, __builtin_amdgcn_readfirstlane(__builtin_bit_cast(int, x)));
}

// Single fused kernel: grid = 128 blocks = B(8) x m-tiles(16); block = 1024 thr
// = 16 waves. Each block computes the COMPLETE n-sum (all 1024 context points)
// for its 64 m's, so there is no second reduce dispatch and no workspace use.
//   - lane <-> m (same 64 m's for all 16 waves); wave w sums n in [64w, 64w+64).
//   - feat/xa for the whole (b) staged once in LDS: feat 1024 rows x 16 floats
//     (padded 15->16, 16B-aligned b128 reads), xa 1024 rows x 4. 80 KB total.
//   - inner-loop ds_reads are all-lanes-same-address -> HW broadcast.
//   - 16 wave-partials combined in LDS (reusing the feat area after a barrier),
//     one coalesced 960-float store straight to out.
// __launch_bounds__(1024,4): 4 waves/EU = 16 waves/CU -> VGPR cap 128; one
// block per CU (LDS 80 KB also caps at 1 block/CU). 128 blocks = 1 round.
// Rationale (round-2 post-mortem): controllable time is per-block/per-dispatch
// fixed cost, not inner-loop throughput -> minimize dispatches and total block
// count, not per-block work.
__global__ __launch_bounds__(1024, 4) void icgp_fused_kernel(
    const float* __restrict__ xa,       // (B, 1024, 1, 3)
    const float* __restrict__ feat,     // (B, 1024, 5, 3)
    const float* __restrict__ xt,       // (B, 1024, 1, 3)
    const float* __restrict__ log_std,  // (1, 5, 3)
    float* __restrict__ out)            // (B, 1024, 5, 3)
{
    // lds[0..16383]      : feat, 1024 rows x 16 (row-padded; reused for combine)
    // lds[16384..20479]  : xa,   1024 rows x 4
    __shared__ float lds[20480];        // 80 KiB

    const int bid  = blockIdx.x;
    const int mt   = bid & 15;          // m-tile (64 m's)
    const int b    = bid >> 4;
    const int tid  = threadIdx.x;
    const int wv   = __builtin_amdgcn_readfirstlane(tid >> 6); // 0..15, uniform
    const int lane = tid & 63;
    const int m    = mt * 64 + lane;

    // ---- stage feat (15360 floats) and xa (3072 floats) into padded LDS ----
    const float* __restrict__ fg = feat + (size_t)b * 15360;  // 16B-aligned
    for (int j = tid; j < 3840; j += 1024) {
        const f4a v = *(const f4a*)(fg + j * 4);
        #pragma unroll
        for (int e = 0; e < 4; ++e) {
            const int g = j * 4 + e;
            const int r = g / 15, c = g - r * 15;
            lds[r * 16 + c] = v[e];
        }
    }
    const float* __restrict__ ag = xa + (size_t)b * 3072;     // 16B-aligned
    if (tid < 768) {
        const f4a v = *(const f4a*)(ag + tid * 4);
        #pragma unroll
        for (int e = 0; e < 4; ++e) {
            const int g = tid * 4 + e;
            const int r = g / 3, c = g - r * 3;
            lds[16384 + r * 4 + c] = v[e];
        }
    }

    // ---- coefficients: wt = exp2(coef*(xa-xt)^2), coef = -0.5*log2e/std^2 ----
    float coef[15];
    #pragma unroll
    for (int kc = 0; kc < 15; ++kc) {
        const float s = __expf(log_std[kc]) + EPS_F;
        coef[kc] = rfl(-0.5f * LOG2E / (s * s));
    }
    bool uni = true;
    #pragma unroll
    for (int k = 1; k < 5; ++k)
        #pragma unroll
        for (int c = 0; c < 3; ++c)
            uni = uni && (coef[k * 3 + c] == coef[c]);

    const float t0 = xt[(b * 1024 + m) * 3 + 0];
    const float t1 = xt[(b * 1024 + m) * 3 + 1];
    const float t2 = xt[(b * 1024 + m) * 3 + 2];

    __syncthreads();

    float acc[15];
    #pragma unroll
    for (int kc = 0; kc < 15; ++kc) acc[kc] = 0.0f;

    const int rb = wv * 64;             // this wave's first LDS row

    if (uni) {
        const float c0 = coef[0], c1 = coef[1], c2 = coef[2];
        #pragma unroll 4
        for (int i = 0; i < 64; ++i) {
            const float* __restrict__ row = &lds[(rb + i) * 16];
            const f4a fA = *(const f4a*)(row);        // kc 0..3
            const f4a fB = *(const f4a*)(row + 4);    // kc 4..7
            const f4a fC = *(const f4a*)(row + 8);    // kc 8..11
            const f4a fD = *(const f4a*)(row + 12);   // kc 12..14 (+pad)
            const f4a av = *(const f4a*)(&lds[16384 + (rb + i) * 4]); // xa (+pad)
            float d0 = av.x - t0; d0 *= d0;
            float d1 = av.y - t1; d1 *= d1;
            float d2 = av.z - t2; d2 *= d2;
            const float w0 = __builtin_amdgcn_exp2f(d0 * c0);
            const float w1 = __builtin_amdgcn_exp2f(d1 * c1);
            const float w2 = __builtin_amdgcn_exp2f(d2 * c2);
            acc[0]  += w0 * fA.x;  acc[1]  += w1 * fA.y;  acc[2]  += w2 * fA.z;
            acc[3]  += w0 * fA.w;  acc[4]  += w1 * fB.x;  acc[5]  += w2 * fB.y;
            acc[6]  += w0 * fB.z;  acc[7]  += w1 * fB.w;  acc[8]  += w2 * fC.x;
            acc[9]  += w0 * fC.y;  acc[10] += w1 * fC.z;  acc[11] += w2 * fC.w;
            acc[12] += w0 * fD.x;  acc[13] += w1 * fD.y;  acc[14] += w2 * fD.z;
        }
    } else {
        // General path: 15 exps per n (correct for arbitrary log_std).
        for (int i = 0; i < 64; ++i) {
            const float* __restrict__ row = &lds[(rb + i) * 16];
            float fv[16];
            *(f4a*)(fv)      = *(const f4a*)(row);
            *(f4a*)(fv + 4)  = *(const f4a*)(row + 4);
            *(f4a*)(fv + 8)  = *(const f4a*)(row + 8);
            *(f4a*)(fv + 12) = *(const f4a*)(row + 12);
            const f4a av = *(const f4a*)(&lds[16384 + (rb + i) * 4]);
            float dd[3];
            dd[0] = av.x - t0; dd[0] *= dd[0];
            dd[1] = av.y - t1; dd[1] *= dd[1];
            dd[2] = av.z - t2; dd[2] *= dd[2];
            #pragma unroll
            for (int k = 0; k < 5; ++k)
                #pragma unroll
                for (int c = 0; c < 3; ++c)
                    acc[k * 3 + c] +=
                        __builtin_amdgcn_exp2f(dd[c] * coef[k * 3 + c]) * fv[k * 3 + c];
        }
    }

    // ---- combine the 16 wave-partials in LDS, store straight to out ----
    __syncthreads();                    // all waves done reading staging
    #pragma unroll
    for (int kc = 0; kc < 15; ++kc)
        lds[wv * 960 + lane * 15 + kc] = acc[kc];   // 15360 floats, feat area
    __syncthreads();

    if (tid < 960) {
        float s = 0.0f;
        #pragma unroll
        for (int w = 0; w < 16; ++w)
            s += lds[w * 960 + tid];                // consecutive lanes -> no conflict
        out[(size_t)b * 15360 + mt * 960 + tid] = s; // coalesced
    }
}

extern "C" void kernel_launch(void* const* d_in, const int* in_sizes, int n_in,
                              void* d_out, int out_size, void* d_ws, size_t ws_size,
                              hipStream_t stream) {
    const float* xa      = (const float*)d_in[0];  // (8,1024,1,3)
    const float* feat    = (const float*)d_in[1];  // (8,1024,5,3)
    const float* xt      = (const float*)d_in[2];  // (8,1024,1,3)
    const float* log_std = (const float*)d_in[3];  // (1,5,3)
    float* out = (float*)d_out;                    // (8,1024,5,3)
    (void)d_ws; (void)ws_size;                     // no workspace: single dispatch

    icgp_fused_kernel<<<dim3(128), dim3(1024), 0, stream>>>(xa, feat, xt, log_std, out);
}

// Round 4
// 74.157 us; speedup vs baseline: 1.0403x; 1.0317x over previous
//
#include <hip/hip_runtime.h>

#define EPS_F 1e-6f
#define LOG2E 1.4426950408889634f

typedef float f4a __attribute__((ext_vector_type(4), aligned(16)));

// Force a (known-uniform) float into an SGPR.
__device__ __forceinline__ float rfl(float x) {
    return __builtin_bit_cast(float, __builtin_amdgcn_readfirstlane(__builtin_bit_cast(int, x)));
}

// Round-4 structure (post-mortem of r3: kernel time is LDS-pipe instruction
// throughput, 5 ds_read_b128 per n-iter per wave at ~12cyc; fix = amortize
// each row-read over 4 m's per lane, and use all 256 CUs):
//   grid = 512 blocks = B(8) x m-groups(4) x n-chunks(16); block = 256 = 4 waves.
//   Each lane owns pm=4 m's: m = mg*256 + p*64 + lane (p=0..3), 4x15 accs.
//   Wave w sums n in [nc*64 + w*16, +16). 512 blocks = 2/CU.
//   LDS/CU: 2 blk x 4 wv x 16 it x 5 reads = 640 instr x ~12cyc ~= 3.2us
//   (was 25.6us in r3); VALU ~2.9us/SIMD -> balanced near the floor.
//   Workspace partials are free: the harness's 268MB poison fill runs
//   unconditionally (r3 proved it: no d_ws use, fill still there).
// __launch_bounds__(256,2): grid only supplies 2 blocks/CU = 2 waves/SIMD, so
// cap VGPR at 256 (no spill risk at ~130 live with unroll 2).
__global__ __launch_bounds__(256, 2) void icgp_partial_kernel(
    const float* __restrict__ xa,       // (B, 1024, 1, 3)
    const float* __restrict__ feat,     // (B, 1024, 5, 3)
    const float* __restrict__ xt,       // (B, 1024, 1, 3)
    const float* __restrict__ log_std,  // (1, 5, 3)
    float* __restrict__ pws)            // (16, B*1024*15) partials
{
    // lds[0..15359]      : combine area, 4 waves x 256 m x 15
    // lds[15360..16383]  : feat staging, 64 rows x 16 (padded 15->16)
    // lds[16384..16639]  : xa staging,   64 rows x 4  (padded 3->4)
    __shared__ float lds[16640];        // 66.6 KB -> 2 blocks/CU fits 160 KB
    const int SF = 15360, SA = 16384;

    const int bid  = blockIdx.x;
    const int nc   = bid & 15;          // n-chunk (64 n's)
    const int mg   = (bid >> 4) & 3;    // m-group (256 m's)
    const int b    = bid >> 6;
    const int tid  = threadIdx.x;
    const int wv   = __builtin_amdgcn_readfirstlane(tid >> 6); // 0..3, uniform
    const int lane = tid & 63;
    const int n0   = nc * 64;

    // ---- stage feat (960 floats) and xa (192 floats) into padded LDS ----
    const float* __restrict__ fg = feat + ((size_t)b * 1024 + n0) * 15; // 16B-aligned
    if (tid < 240) {
        const f4a v = *(const f4a*)(fg + tid * 4);
        #pragma unroll
        for (int e = 0; e < 4; ++e) {
            const int g = tid * 4 + e;
            const int r = g / 15, c = g - r * 15;
            lds[SF + r * 16 + c] = v[e];
        }
    }
    const float* __restrict__ ag = xa + ((size_t)b * 1024 + n0) * 3;    // 16B-aligned
    if (tid < 48) {
        const f4a v = *(const f4a*)(ag + tid * 4);
        #pragma unroll
        for (int e = 0; e < 4; ++e) {
            const int g = tid * 4 + e;
            const int r = g / 3, c = g - r * 3;
            lds[SA + r * 4 + c] = v[e];
        }
    }

    // ---- coefficients: wt = exp2(coef*(xa-xt)^2), coef = -0.5*log2e/std^2 ----
    float coef[15];
    #pragma unroll
    for (int kc = 0; kc < 15; ++kc) {
        const float s = __expf(log_std[kc]) + EPS_F;
        coef[kc] = rfl(-0.5f * LOG2E / (s * s));
    }
    bool uni = true;
    #pragma unroll
    for (int k = 1; k < 5; ++k)
        #pragma unroll
        for (int c = 0; c < 3; ++c)
            uni = uni && (coef[k * 3 + c] == coef[c]);

    // xt for this lane's 4 m's: m = mg*256 + p*64 + lane (coalesced loads)
    float t[4][3];
    #pragma unroll
    for (int p = 0; p < 4; ++p) {
        const int m = mg * 256 + p * 64 + lane;
        t[p][0] = xt[(b * 1024 + m) * 3 + 0];
        t[p][1] = xt[(b * 1024 + m) * 3 + 1];
        t[p][2] = xt[(b * 1024 + m) * 3 + 2];
    }

    __syncthreads();

    float acc[4][15];
    #pragma unroll
    for (int p = 0; p < 4; ++p)
        #pragma unroll
        for (int kc = 0; kc < 15; ++kc) acc[p][kc] = 0.0f;

    const int rb = wv * 16;             // this wave's first staging row

    if (uni) {
        const float c0 = coef[0], c1 = coef[1], c2 = coef[2];
        #pragma unroll 2
        for (int i = 0; i < 16; ++i) {
            const float* __restrict__ row = &lds[SF + (rb + i) * 16];
            const f4a fA = *(const f4a*)(row);        // kc 0..3
            const f4a fB = *(const f4a*)(row + 4);    // kc 4..7
            const f4a fC = *(const f4a*)(row + 8);    // kc 8..11
            const f4a fD = *(const f4a*)(row + 12);   // kc 12..14 (+pad)
            const f4a av = *(const f4a*)(&lds[SA + (rb + i) * 4]); // xa (+pad)
            #pragma unroll
            for (int p = 0; p < 4; ++p) {
                float d0 = av.x - t[p][0]; d0 *= d0;
                float d1 = av.y - t[p][1]; d1 *= d1;
                float d2 = av.z - t[p][2]; d2 *= d2;
                const float w0 = __builtin_amdgcn_exp2f(d0 * c0);
                const float w1 = __builtin_amdgcn_exp2f(d1 * c1);
                const float w2 = __builtin_amdgcn_exp2f(d2 * c2);
                acc[p][0]  += w0 * fA.x;  acc[p][1]  += w1 * fA.y;  acc[p][2]  += w2 * fA.z;
                acc[p][3]  += w0 * fA.w;  acc[p][4]  += w1 * fB.x;  acc[p][5]  += w2 * fB.y;
                acc[p][6]  += w0 * fB.z;  acc[p][7]  += w1 * fB.w;  acc[p][8]  += w2 * fC.x;
                acc[p][9]  += w0 * fC.y;  acc[p][10] += w1 * fC.z;  acc[p][11] += w2 * fC.w;
                acc[p][12] += w0 * fD.x;  acc[p][13] += w1 * fD.y;  acc[p][14] += w2 * fD.z;
            }
        }
    } else {
        // General path: 15 exps per (m,n) (correct for arbitrary log_std).
        for (int i = 0; i < 16; ++i) {
            const float* __restrict__ row = &lds[SF + (rb + i) * 16];
            float fv[16];
            *(f4a*)(fv)      = *(const f4a*)(row);
            *(f4a*)(fv + 4)  = *(const f4a*)(row + 4);
            *(f4a*)(fv + 8)  = *(const f4a*)(row + 8);
            *(f4a*)(fv + 12) = *(const f4a*)(row + 12);
            const f4a av = *(const f4a*)(&lds[SA + (rb + i) * 4]);
            #pragma unroll
            for (int p = 0; p < 4; ++p) {
                float dd[3];
                dd[0] = av.x - t[p][0]; dd[0] *= dd[0];
                dd[1] = av.y - t[p][1]; dd[1] *= dd[1];
                dd[2] = av.z - t[p][2]; dd[2] *= dd[2];
                #pragma unroll
                for (int k = 0; k < 5; ++k)
                    #pragma unroll
                    for (int c = 0; c < 3; ++c)
                        acc[p][k * 3 + c] +=
                            __builtin_amdgcn_exp2f(dd[c] * coef[k * 3 + c]) * fv[k * 3 + c];
            }
        }
    }

    // ---- combine the 4 wave-partials in LDS, coalesced store to pws ----
    __syncthreads();                    // all waves done reading staging
    #pragma unroll
    for (int p = 0; p < 4; ++p)
        #pragma unroll
        for (int kc = 0; kc < 15; ++kc)
            lds[wv * 3840 + (p * 64 + lane) * 15 + kc] = acc[p][kc];
    __syncthreads();

    float* __restrict__ pb = pws + (size_t)nc * 122880
                                 + ((size_t)b * 1024 + mg * 256) * 15;
    #pragma unroll
    for (int j = 0; j < 15; ++j) {
        const int oidx = j * 256 + tid;         // 0..3839, exact
        float s = 0.0f;
        #pragma unroll
        for (int w = 0; w < 4; ++w)
            s += lds[w * 3840 + oidx];
        pb[oidx] = s;                            // coalesced
    }
}

// Kernel 2: sum the 16 n-chunk slices, float4-vectorized, fully coalesced.
// 30720 float4 outputs = 120 blocks x 256 threads.
__global__ __launch_bounds__(256) void icgp_reduce_kernel(
    const float* __restrict__ pws, float* __restrict__ out)
{
    const int idx4 = blockIdx.x * 256 + threadIdx.x;   // < 30720
    const f4a* __restrict__ p4 = (const f4a*)pws;
    f4a s = {0.0f, 0.0f, 0.0f, 0.0f};
    #pragma unroll
    for (int ns = 0; ns < 16; ++ns) {
        const f4a v = p4[(size_t)ns * 30720 + idx4];
        s.x += v.x; s.y += v.y; s.z += v.z; s.w += v.w;
    }
    ((f4a*)out)[idx4] = s;
}

extern "C" void kernel_launch(void* const* d_in, const int* in_sizes, int n_in,
                              void* d_out, int out_size, void* d_ws, size_t ws_size,
                              hipStream_t stream) {
    const float* xa      = (const float*)d_in[0];  // (8,1024,1,3)
    const float* feat    = (const float*)d_in[1];  // (8,1024,5,3)
    const float* xt      = (const float*)d_in[2];  // (8,1024,1,3)
    const float* log_std = (const float*)d_in[3];  // (1,5,3)
    float* out = (float*)d_out;                    // (8,1024,5,3)
    float* pws = (float*)d_ws;                     // 16 x 122880 floats = 7.86 MB

    icgp_partial_kernel<<<dim3(512), dim3(256), 0, stream>>>(xa, feat, xt, log_std, pws);
    icgp_reduce_kernel<<<dim3(120), dim3(256), 0, stream>>>(pws, out);
}